// Round 12
// baseline (2182.443 us; speedup 1.0000x reference)
//
#include <hip/hip_runtime.h>
#include <math.h>

#define NVERT 5023
#define NV3   15069
#define NEXP  50
#define NPF   36
#define NJ    5
#define KK    86

// ws float layout:
//   part: [0 .. 126*800)    per-block JSD partials
//   wsJ:  [100800 .. 101600)
//   Gt:   [101632 .. 101632 + 86*B)   Gt[k][b] = (k<50? expr[b][k] : pf[b][k-50])
#define JBLK 126
#define JCH  40
#define PSTR 800
#define WSJ  (JBLK * PSTR)
#define GT_OFF 101632

__global__ __launch_bounds__(160) void k_jreg(const float* __restrict__ Jr,
                                              const float* __restrict__ sd,
                                              const float* __restrict__ vt,
                                              float* __restrict__ ws) {
  int t = threadIdx.x;
  if (t >= 153) return;
  int v0 = blockIdx.x * JCH;
  int v1 = min(NVERT, v0 + JCH);
  float acc[NJ] = {0.f, 0.f, 0.f, 0.f, 0.f};
  float* pb = ws + blockIdx.x * PSTR;
  if (t < 150) {
    int k = t / 50, e = t - k * 50;
    const float* base = sd + k * 150 + 100 + e;
    int v = v0;
    for (; v + 4 <= v1; v += 4) {
      float s0 = base[(size_t)(v + 0) * 450];
      float s1 = base[(size_t)(v + 1) * 450];
      float s2 = base[(size_t)(v + 2) * 450];
      float s3 = base[(size_t)(v + 3) * 450];
#pragma unroll
      for (int j = 0; j < NJ; ++j) {
        acc[j] = fmaf(Jr[j * NVERT + v + 0], s0, acc[j]);
        acc[j] = fmaf(Jr[j * NVERT + v + 1], s1, acc[j]);
        acc[j] = fmaf(Jr[j * NVERT + v + 2], s2, acc[j]);
        acc[j] = fmaf(Jr[j * NVERT + v + 3], s3, acc[j]);
      }
    }
    for (; v < v1; ++v) {
      float s = base[(size_t)v * 450];
#pragma unroll
      for (int j = 0; j < NJ; ++j)
        acc[j] = fmaf(Jr[j * NVERT + v], s, acc[j]);
    }
#pragma unroll
    for (int j = 0; j < NJ; ++j) pb[j * 160 + t] = acc[j];
  } else {
    int k = t - 150;
    for (int v = v0; v < v1; ++v) {
      float s = vt[v * 3 + k];
#pragma unroll
      for (int j = 0; j < NJ; ++j)
        acc[j] = fmaf(Jr[j * NVERT + v], s, acc[j]);
    }
#pragma unroll
    for (int j = 0; j < NJ; ++j) pb[j * 160 + 150 + k] = acc[j];
  }
}

__global__ __launch_bounds__(256) void k_jred(float* __restrict__ ws) {
  int o = blockIdx.x * 256 + threadIdx.x;
  if (o >= 765) return;
  int j = o / 153, t = o - j * 153;
  int off = j * 160 + t;
  float s = 0.f;
#pragma unroll 6
  for (int bk = 0; bk < JBLK; ++bk) s += ws[bk * PSTR + off];
  ws[WSJ + off] = s;
}

// one thread per batch; also writes Gt (transposed expr|pf) for k_vert
__global__ __launch_bounds__(64) void k_pose(const float* __restrict__ expr,
                                             const float* __restrict__ pose,
                                             float* __restrict__ ws,
                                             float* __restrict__ out_pf,
                                             float* __restrict__ out_A,
                                             int B) {
  __shared__ float pf_s[64 * 36];
  __shared__ float A_s[64 * 80];
  int t = threadIdx.x;
  int b0 = blockIdx.x * 64;
  int b = b0 + t;
  const float* wsJ = ws + WSJ;
  float* Gt = ws + GT_OFF;

  if (b < B) {
    float R[5][9];
#pragma unroll
    for (int j = 0; j < 5; ++j) {
      float x = pose[b * 15 + j * 3 + 0];
      float y = pose[b * 15 + j * 3 + 1];
      float z = pose[b * 15 + j * 3 + 2];
      float ax = x + 1e-8f, ay = y + 1e-8f, az = z + 1e-8f;
      float ang = sqrtf(ax * ax + ay * ay + az * az);
      float inv = 1.0f / ang;
      float ux = x * inv, uy = y * inv, uz = z * inv;
      float s = __sinf(ang), c = __cosf(ang), t1 = 1.0f - c;
      R[j][0] = 1.0f - t1 * (uy * uy + uz * uz);
      R[j][1] = t1 * ux * uy - s * uz;
      R[j][2] = t1 * ux * uz + s * uy;
      R[j][3] = t1 * ux * uy + s * uz;
      R[j][4] = 1.0f - t1 * (ux * ux + uz * uz);
      R[j][5] = t1 * uy * uz - s * ux;
      R[j][6] = t1 * ux * uz - s * uy;
      R[j][7] = t1 * uy * uz + s * ux;
      R[j][8] = 1.0f - t1 * (ux * ux + uy * uy);
    }

#pragma unroll
    for (int j = 1; j < 5; ++j)
#pragma unroll
      for (int i = 0; i < 9; ++i)
        pf_s[t * 36 + (j - 1) * 9 + i] =
            R[j][i] - ((i == 0 || i == 4 || i == 8) ? 1.0f : 0.0f);

    float jnt[5][3];
#pragma unroll
    for (int j = 0; j < 5; ++j)
#pragma unroll
      for (int k = 0; k < 3; ++k) jnt[j][k] = wsJ[j * 160 + 150 + k];
    for (int e = 0; e < NEXP; ++e) {
      float ex = expr[b * NEXP + e];
#pragma unroll
      for (int j = 0; j < 5; ++j)
#pragma unroll
        for (int k = 0; k < 3; ++k)
          jnt[j][k] = fmaf(ex, wsJ[j * 160 + k * 50 + e], jnt[j][k]);
    }

    float* Ab = A_s + t * 80;
#pragma unroll
    for (int r = 0; r < 3; ++r) {
      float tj = R[0][r * 3 + 0] * jnt[0][0] + R[0][r * 3 + 1] * jnt[0][1] +
                 R[0][r * 3 + 2] * jnt[0][2];
      Ab[r * 4 + 0] = R[0][r * 3 + 0];
      Ab[r * 4 + 1] = R[0][r * 3 + 1];
      Ab[r * 4 + 2] = R[0][r * 3 + 2];
      Ab[r * 4 + 3] = jnt[0][r] - tj;
    }
    Ab[12] = 0.f; Ab[13] = 0.f; Ab[14] = 0.f; Ab[15] = 1.f;

    float C1R[9], C1t[3];
    {
      float rel[3] = {jnt[1][0] - jnt[0][0], jnt[1][1] - jnt[0][1],
                      jnt[1][2] - jnt[0][2]};
#pragma unroll
      for (int r = 0; r < 3; ++r) {
#pragma unroll
        for (int c = 0; c < 3; ++c)
          C1R[r * 3 + c] = R[0][r * 3 + 0] * R[1][0 + c] +
                           R[0][r * 3 + 1] * R[1][3 + c] +
                           R[0][r * 3 + 2] * R[1][6 + c];
        C1t[r] = R[0][r * 3 + 0] * rel[0] + R[0][r * 3 + 1] * rel[1] +
                 R[0][r * 3 + 2] * rel[2] + jnt[0][r];
      }
      float* A1 = Ab + 16;
#pragma unroll
      for (int r = 0; r < 3; ++r) {
        float tj = C1R[r * 3 + 0] * jnt[1][0] + C1R[r * 3 + 1] * jnt[1][1] +
                   C1R[r * 3 + 2] * jnt[1][2];
        A1[r * 4 + 0] = C1R[r * 3 + 0];
        A1[r * 4 + 1] = C1R[r * 3 + 1];
        A1[r * 4 + 2] = C1R[r * 3 + 2];
        A1[r * 4 + 3] = C1t[r] - tj;
      }
      A1[12] = 0.f; A1[13] = 0.f; A1[14] = 0.f; A1[15] = 1.f;
    }

#pragma unroll
    for (int i = 2; i < 5; ++i) {
      float rel[3] = {jnt[i][0] - jnt[1][0], jnt[i][1] - jnt[1][1],
                      jnt[i][2] - jnt[1][2]};
      float CiR[9], Cit[3];
#pragma unroll
      for (int r = 0; r < 3; ++r) {
#pragma unroll
        for (int c = 0; c < 3; ++c)
          CiR[r * 3 + c] = C1R[r * 3 + 0] * R[i][0 + c] +
                           C1R[r * 3 + 1] * R[i][3 + c] +
                           C1R[r * 3 + 2] * R[i][6 + c];
        Cit[r] = C1R[r * 3 + 0] * rel[0] + C1R[r * 3 + 1] * rel[1] +
                 C1R[r * 3 + 2] * rel[2] + C1t[r];
      }
      float* Ai = Ab + i * 16;
#pragma unroll
      for (int r = 0; r < 3; ++r) {
        float tj = CiR[r * 3 + 0] * jnt[i][0] + CiR[r * 3 + 1] * jnt[i][1] +
                   CiR[r * 3 + 2] * jnt[i][2];
        Ai[r * 4 + 0] = CiR[r * 3 + 0];
        Ai[r * 4 + 1] = CiR[r * 3 + 1];
        Ai[r * 4 + 2] = CiR[r * 3 + 2];
        Ai[r * 4 + 3] = Cit[r] - tj;
      }
      Ai[12] = 0.f; Ai[13] = 0.f; Ai[14] = 0.f; Ai[15] = 1.f;
    }
  }
  __syncthreads();
  // coalesced copy-out
  for (int r = 0; r < 36; ++r)
    out_pf[(size_t)b0 * 36 + r * 64 + t] = pf_s[r * 64 + t];
  for (int r = 0; r < 80; ++r)
    out_A[(size_t)b0 * 80 + r * 64 + t] = A_s[r * 64 + t];
  // Gt rows (coalesced across lanes per k)
  if (b < B) {
    for (int k = 0; k < NEXP; ++k)
      Gt[(size_t)k * B + b] = expr[(size_t)b * NEXP + k];
    for (int k = 0; k < NPF; ++k)
      Gt[(size_t)(NEXP + k) * B + b] = pf_s[t * 36 + k];
  }
}

// Fused blend+skin: thread = one column, registers = 8 batch accumulators.
// Inner loop: 1 conflict-free ds_read_b32 + 2 wave-uniform float4 Gt loads
// + 8 FMA -> no LDS-BW cap, no bank conflicts (R10 diagnosis).
#define VBN 120   // cols per block (divisible by 3!)
#define VBB 128   // batches per block
#define VCH 8     // batches per chunk (register accumulators)
__global__ __launch_bounds__(128) void k_vert(const float* __restrict__ vt,
                                              const float* __restrict__ sd,
                                              const float* __restrict__ pd,
                                              const float* __restrict__ w,
                                              const float* __restrict__ A,
                                              const float* __restrict__ Gt,
                                              float* __restrict__ out, int B) {
  __shared__ float Ss[KK * VBN];                    // 41280 B
  __shared__ __align__(16) float Cs[VCH][VBN + 4];  // 3968 B
  __shared__ __align__(16) float As[VCH * 80];      // 2560 B
  int tid = threadIdx.x;
  int b0 = blockIdx.x * VBB;
  int i0 = blockIdx.y * VBN;
  int vbase = i0 / 3;

  // ---- stage S[86][120]: r<50 shapedirs (expr cols), r>=50 posedirs
  for (int idx = tid; idx < 22 * VBN; idx += 128) {
    int rq = idx / VBN, col = idx - rq * VBN;
    int ig = min(i0 + col, NV3 - 1);
    int v = ig / 3, kc = ig - 3 * v;
#pragma unroll
    for (int q = 0; q < 4; ++q) {
      int r = rq * 4 + q;
      if (r < KK)
        Ss[r * VBN + col] = (r < 50) ? sd[(size_t)v * 450 + kc * 150 + 100 + r]
                                     : pd[(size_t)(r - 50) * NV3 + ig];
    }
  }

  bool act = tid < VBN;
  int col = act ? tid : 0;
  int gcol = i0 + col;
  bool valid = act && (gcol < NV3);
  int gc = min(gcol, NV3 - 1);
  int vloc = col / 3;
  int q = col - 3 * vloc;
  int colq = 3 * vloc;                 // local col of component 0
  int vw = min(vbase + vloc, NVERT - 1);
  const float* wp = w + (size_t)vw * 5;
  float wr0 = wp[0], wr1 = wp[1], wr2 = wp[2], wr3 = wp[3], wr4 = wp[4];
  float vtr = vt[gc];
  __syncthreads();                     // Ss ready

  int nch = VBB / VCH;
  for (int ch = 0; ch < nch; ++ch) {
    int bb = b0 + ch * VCH;
    // issue A-chunk loads early (640 floats, coalesced) -> regs
    float ar0 = A[(size_t)bb * 80 + tid];
    float ar1 = A[(size_t)bb * 80 + tid + 128];
    float ar2 = A[(size_t)bb * 80 + tid + 256];
    float ar3 = A[(size_t)bb * 80 + tid + 384];
    float ar4 = A[(size_t)bb * 80 + tid + 512];
    // GEMM over K=86: 8 batch accumulators
    float a0 = vtr, a1 = vtr, a2 = vtr, a3 = vtr;
    float a4 = vtr, a5 = vtr, a6 = vtr, a7 = vtr;
    const float* gtb = Gt + bb;
#pragma unroll
    for (int k = 0; k < KK; ++k) {
      float sv = Ss[k * VBN + col];
      float4 g0 = *(const float4*)(gtb + (size_t)k * B);
      float4 g1 = *(const float4*)(gtb + (size_t)k * B + 4);
      a0 = fmaf(g0.x, sv, a0); a1 = fmaf(g0.y, sv, a1);
      a2 = fmaf(g0.z, sv, a2); a3 = fmaf(g0.w, sv, a3);
      a4 = fmaf(g1.x, sv, a4); a5 = fmaf(g1.y, sv, a5);
      a6 = fmaf(g1.z, sv, a6); a7 = fmaf(g1.w, sv, a7);
    }
    __syncthreads();                   // previous chunk's skin done with Cs/As
    As[tid]       = ar0;  As[tid + 128] = ar1;  As[tid + 256] = ar2;
    As[tid + 384] = ar3;  As[tid + 512] = ar4;
    if (act) {
      Cs[0][col] = a0; Cs[1][col] = a1; Cs[2][col] = a2; Cs[3][col] = a3;
      Cs[4][col] = a4; Cs[5][col] = a5; Cs[6][col] = a6; Cs[7][col] = a7;
    }
    __syncthreads();                   // Cs/As ready
    // skinning: T row q = sum_j w_j * A[b][j][q][:], then dot v_posed
    if (valid) {
#pragma unroll
      for (int j = 0; j < VCH; ++j) {
        const float* Ab = As + j * 80 + q * 4;
        float4 A0 = *(const float4*)(Ab);
        float4 A1 = *(const float4*)(Ab + 16);
        float4 A2 = *(const float4*)(Ab + 32);
        float4 A3 = *(const float4*)(Ab + 48);
        float4 A4 = *(const float4*)(Ab + 64);
        float T0 = fmaf(wr4, A4.x, fmaf(wr3, A3.x,
                   fmaf(wr2, A2.x, fmaf(wr1, A1.x, wr0 * A0.x))));
        float T1 = fmaf(wr4, A4.y, fmaf(wr3, A3.y,
                   fmaf(wr2, A2.y, fmaf(wr1, A1.y, wr0 * A0.y))));
        float T2 = fmaf(wr4, A4.z, fmaf(wr3, A3.z,
                   fmaf(wr2, A2.z, fmaf(wr1, A1.z, wr0 * A0.z))));
        float T3 = fmaf(wr4, A4.w, fmaf(wr3, A3.w,
                   fmaf(wr2, A2.w, fmaf(wr1, A1.w, wr0 * A0.w))));
        float x0 = Cs[j][colq], x1 = Cs[j][colq + 1], x2 = Cs[j][colq + 2];
        out[(size_t)(bb + j) * NV3 + gcol] =
            fmaf(T0, x0, fmaf(T1, x1, fmaf(T2, x2, T3)));
      }
    }
  }
}

extern "C" void kernel_launch(void* const* d_in, const int* in_sizes, int n_in,
                              void* d_out, int out_size, void* d_ws,
                              size_t ws_size, hipStream_t stream) {
  const float* expr = (const float*)d_in[0];
  const float* pose = (const float*)d_in[1];
  const float* vt   = (const float*)d_in[2];
  const float* sd   = (const float*)d_in[3];
  const float* pd   = (const float*)d_in[4];
  const float* Jr   = (const float*)d_in[5];
  const float* w    = (const float*)d_in[6];
  int B = in_sizes[0] / NEXP;

  float* out    = (float*)d_out;
  float* out_pf = out + (size_t)B * NV3;
  float* out_A  = out_pf + (size_t)B * NPF;
  float* ws     = (float*)d_ws;

  k_jreg<<<dim3(JBLK), 160, 0, stream>>>(Jr, sd, vt, ws);
  k_jred<<<dim3(3), 256, 0, stream>>>(ws);
  k_pose<<<dim3((B + 63) / 64), 64, 0, stream>>>(expr, pose, ws, out_pf,
                                                 out_A, B);
  k_vert<<<dim3((B + VBB - 1) / VBB, (NV3 + VBN - 1) / VBN), 128, 0, stream>>>(
      vt, sd, pd, w, out_A, ws + GT_OFF, out, B);
}

// Round 13
// 652.535 us; speedup vs baseline: 3.3446x; 3.3446x over previous
//
#include <hip/hip_runtime.h>
#include <math.h>

#define NVERT 5023
#define NV3   15069
#define NEXP  50
#define NPF   36
#define NJ    5
#define KK    86

// ws float layout:
//   part: [0 .. 126*800)    per-block JSD partials
//   wsJ:  [100800 .. 101600)
//   Gt:   [101632 .. 101632 + 86*B)   Gt[k][b] = (k<50? expr[b][k] : pf[b][k-50])
#define JBLK 126
#define JCH  40
#define PSTR 800
#define WSJ  (JBLK * PSTR)
#define GT_OFF 101632

__global__ __launch_bounds__(160) void k_jreg(const float* __restrict__ Jr,
                                              const float* __restrict__ sd,
                                              const float* __restrict__ vt,
                                              float* __restrict__ ws) {
  int t = threadIdx.x;
  if (t >= 153) return;
  int v0 = blockIdx.x * JCH;
  int v1 = min(NVERT, v0 + JCH);
  float acc[NJ] = {0.f, 0.f, 0.f, 0.f, 0.f};
  float* pb = ws + blockIdx.x * PSTR;
  if (t < 150) {
    int k = t / 50, e = t - k * 50;
    const float* base = sd + k * 150 + 100 + e;
    int v = v0;
    for (; v + 4 <= v1; v += 4) {
      float s0 = base[(size_t)(v + 0) * 450];
      float s1 = base[(size_t)(v + 1) * 450];
      float s2 = base[(size_t)(v + 2) * 450];
      float s3 = base[(size_t)(v + 3) * 450];
#pragma unroll
      for (int j = 0; j < NJ; ++j) {
        acc[j] = fmaf(Jr[j * NVERT + v + 0], s0, acc[j]);
        acc[j] = fmaf(Jr[j * NVERT + v + 1], s1, acc[j]);
        acc[j] = fmaf(Jr[j * NVERT + v + 2], s2, acc[j]);
        acc[j] = fmaf(Jr[j * NVERT + v + 3], s3, acc[j]);
      }
    }
    for (; v < v1; ++v) {
      float s = base[(size_t)v * 450];
#pragma unroll
      for (int j = 0; j < NJ; ++j)
        acc[j] = fmaf(Jr[j * NVERT + v], s, acc[j]);
    }
#pragma unroll
    for (int j = 0; j < NJ; ++j) pb[j * 160 + t] = acc[j];
  } else {
    int k = t - 150;
    for (int v = v0; v < v1; ++v) {
      float s = vt[v * 3 + k];
#pragma unroll
      for (int j = 0; j < NJ; ++j)
        acc[j] = fmaf(Jr[j * NVERT + v], s, acc[j]);
    }
#pragma unroll
    for (int j = 0; j < NJ; ++j) pb[j * 160 + 150 + k] = acc[j];
  }
}

__global__ __launch_bounds__(256) void k_jred(float* __restrict__ ws) {
  int o = blockIdx.x * 256 + threadIdx.x;
  if (o >= 765) return;
  int j = o / 153, t = o - j * 153;
  int off = j * 160 + t;
  float s = 0.f;
#pragma unroll 6
  for (int bk = 0; bk < JBLK; ++bk) s += ws[bk * PSTR + off];
  ws[WSJ + off] = s;
}

// one thread per batch; also writes Gt (transposed expr|pf) for k_vert
__global__ __launch_bounds__(64) void k_pose(const float* __restrict__ expr,
                                             const float* __restrict__ pose,
                                             float* __restrict__ ws,
                                             float* __restrict__ out_pf,
                                             float* __restrict__ out_A,
                                             int B) {
  __shared__ float pf_s[64 * 36];
  __shared__ float A_s[64 * 80];
  int t = threadIdx.x;
  int b0 = blockIdx.x * 64;
  int b = b0 + t;
  const float* wsJ = ws + WSJ;
  float* Gt = ws + GT_OFF;

  if (b < B) {
    float R[5][9];
#pragma unroll
    for (int j = 0; j < 5; ++j) {
      float x = pose[b * 15 + j * 3 + 0];
      float y = pose[b * 15 + j * 3 + 1];
      float z = pose[b * 15 + j * 3 + 2];
      float ax = x + 1e-8f, ay = y + 1e-8f, az = z + 1e-8f;
      float ang = sqrtf(ax * ax + ay * ay + az * az);
      float inv = 1.0f / ang;
      float ux = x * inv, uy = y * inv, uz = z * inv;
      float s = __sinf(ang), c = __cosf(ang), t1 = 1.0f - c;
      R[j][0] = 1.0f - t1 * (uy * uy + uz * uz);
      R[j][1] = t1 * ux * uy - s * uz;
      R[j][2] = t1 * ux * uz + s * uy;
      R[j][3] = t1 * ux * uy + s * uz;
      R[j][4] = 1.0f - t1 * (ux * ux + uz * uz);
      R[j][5] = t1 * uy * uz - s * ux;
      R[j][6] = t1 * ux * uz - s * uy;
      R[j][7] = t1 * uy * uz + s * ux;
      R[j][8] = 1.0f - t1 * (ux * ux + uy * uy);
    }

#pragma unroll
    for (int j = 1; j < 5; ++j)
#pragma unroll
      for (int i = 0; i < 9; ++i)
        pf_s[t * 36 + (j - 1) * 9 + i] =
            R[j][i] - ((i == 0 || i == 4 || i == 8) ? 1.0f : 0.0f);

    float jnt[5][3];
#pragma unroll
    for (int j = 0; j < 5; ++j)
#pragma unroll
      for (int k = 0; k < 3; ++k) jnt[j][k] = wsJ[j * 160 + 150 + k];
    for (int e = 0; e < NEXP; ++e) {
      float ex = expr[b * NEXP + e];
#pragma unroll
      for (int j = 0; j < 5; ++j)
#pragma unroll
        for (int k = 0; k < 3; ++k)
          jnt[j][k] = fmaf(ex, wsJ[j * 160 + k * 50 + e], jnt[j][k]);
    }

    float* Ab = A_s + t * 80;
#pragma unroll
    for (int r = 0; r < 3; ++r) {
      float tj = R[0][r * 3 + 0] * jnt[0][0] + R[0][r * 3 + 1] * jnt[0][1] +
                 R[0][r * 3 + 2] * jnt[0][2];
      Ab[r * 4 + 0] = R[0][r * 3 + 0];
      Ab[r * 4 + 1] = R[0][r * 3 + 1];
      Ab[r * 4 + 2] = R[0][r * 3 + 2];
      Ab[r * 4 + 3] = jnt[0][r] - tj;
    }
    Ab[12] = 0.f; Ab[13] = 0.f; Ab[14] = 0.f; Ab[15] = 1.f;

    float C1R[9], C1t[3];
    {
      float rel[3] = {jnt[1][0] - jnt[0][0], jnt[1][1] - jnt[0][1],
                      jnt[1][2] - jnt[0][2]};
#pragma unroll
      for (int r = 0; r < 3; ++r) {
#pragma unroll
        for (int c = 0; c < 3; ++c)
          C1R[r * 3 + c] = R[0][r * 3 + 0] * R[1][0 + c] +
                           R[0][r * 3 + 1] * R[1][3 + c] +
                           R[0][r * 3 + 2] * R[1][6 + c];
        C1t[r] = R[0][r * 3 + 0] * rel[0] + R[0][r * 3 + 1] * rel[1] +
                 R[0][r * 3 + 2] * rel[2] + jnt[0][r];
      }
      float* A1 = Ab + 16;
#pragma unroll
      for (int r = 0; r < 3; ++r) {
        float tj = C1R[r * 3 + 0] * jnt[1][0] + C1R[r * 3 + 1] * jnt[1][1] +
                   C1R[r * 3 + 2] * jnt[1][2];
        A1[r * 4 + 0] = C1R[r * 3 + 0];
        A1[r * 4 + 1] = C1R[r * 3 + 1];
        A1[r * 4 + 2] = C1R[r * 3 + 2];
        A1[r * 4 + 3] = C1t[r] - tj;
      }
      A1[12] = 0.f; A1[13] = 0.f; A1[14] = 0.f; A1[15] = 1.f;
    }

#pragma unroll
    for (int i = 2; i < 5; ++i) {
      float rel[3] = {jnt[i][0] - jnt[1][0], jnt[i][1] - jnt[1][1],
                      jnt[i][2] - jnt[1][2]};
      float CiR[9], Cit[3];
#pragma unroll
      for (int r = 0; r < 3; ++r) {
#pragma unroll
        for (int c = 0; c < 3; ++c)
          CiR[r * 3 + c] = C1R[r * 3 + 0] * R[i][0 + c] +
                           C1R[r * 3 + 1] * R[i][3 + c] +
                           C1R[r * 3 + 2] * R[i][6 + c];
        Cit[r] = C1R[r * 3 + 0] * rel[0] + C1R[r * 3 + 1] * rel[1] +
                 C1R[r * 3 + 2] * rel[2] + C1t[r];
      }
      float* Ai = Ab + i * 16;
#pragma unroll
      for (int r = 0; r < 3; ++r) {
        float tj = CiR[r * 3 + 0] * jnt[i][0] + CiR[r * 3 + 1] * jnt[i][1] +
                   CiR[r * 3 + 2] * jnt[i][2];
        Ai[r * 4 + 0] = CiR[r * 3 + 0];
        Ai[r * 4 + 1] = CiR[r * 3 + 1];
        Ai[r * 4 + 2] = CiR[r * 3 + 2];
        Ai[r * 4 + 3] = Cit[r] - tj;
      }
      Ai[12] = 0.f; Ai[13] = 0.f; Ai[14] = 0.f; Ai[15] = 1.f;
    }
  }
  __syncthreads();
  // coalesced copy-out
  for (int r = 0; r < 36; ++r)
    out_pf[(size_t)b0 * 36 + r * 64 + t] = pf_s[r * 64 + t];
  for (int r = 0; r < 80; ++r)
    out_A[(size_t)b0 * 80 + r * 64 + t] = A_s[r * 64 + t];
  // Gt rows (coalesced across lanes per k)
  if (b < B) {
    for (int k = 0; k < NEXP; ++k)
      Gt[(size_t)k * B + b] = expr[(size_t)b * NEXP + k];
    for (int k = 0; k < NPF; ++k)
      Gt[(size_t)(NEXP + k) * B + b] = pf_s[t * 36 + k];
  }
}

// Fused blend+skin: thread = one column, registers = 8 batch accumulators.
// Inner loop: 1 conflict-free ds_read_b32 + 2 wave-uniform float4 Gt loads
// + 8 FMA. NOTE: k-loop unroll is capped at 2 — full unroll (R12) fully
// unrolled 86 iters of float4 loads -> 256 VGPR cap + scratch spills ->
// 5.35 GB HBM traffic/dispatch, 2 ms. Accumulator ILP (8) already hides
// latency; deep unroll only adds pressure.
#define VBN 120   // cols per block (divisible by 3!)
#define VBB 128   // batches per block
#define VCH 8     // batches per chunk (register accumulators)
__global__ __launch_bounds__(128) void k_vert(const float* __restrict__ vt,
                                              const float* __restrict__ sd,
                                              const float* __restrict__ pd,
                                              const float* __restrict__ w,
                                              const float* __restrict__ A,
                                              const float* __restrict__ Gt,
                                              float* __restrict__ out, int B) {
  __shared__ float Ss[KK * VBN];                    // 41280 B
  __shared__ __align__(16) float Cs[VCH][VBN + 4];  // 3968 B
  __shared__ __align__(16) float As[VCH * 80];      // 2560 B
  int tid = threadIdx.x;
  int b0 = blockIdx.x * VBB;
  int i0 = blockIdx.y * VBN;
  int vbase = i0 / 3;

  // ---- stage S[86][120]: r<50 shapedirs (expr cols), r>=50 posedirs
  for (int idx = tid; idx < 22 * VBN; idx += 128) {
    int rq = idx / VBN, col = idx - rq * VBN;
    int ig = min(i0 + col, NV3 - 1);
    int v = ig / 3, kc = ig - 3 * v;
#pragma unroll
    for (int q = 0; q < 4; ++q) {
      int r = rq * 4 + q;
      if (r < KK)
        Ss[r * VBN + col] = (r < 50) ? sd[(size_t)v * 450 + kc * 150 + 100 + r]
                                     : pd[(size_t)(r - 50) * NV3 + ig];
    }
  }

  bool act = tid < VBN;
  int col = act ? tid : 0;
  int gcol = i0 + col;
  bool valid = act && (gcol < NV3);
  int gc = min(gcol, NV3 - 1);
  int vloc = col / 3;
  int q = col - 3 * vloc;
  int colq = 3 * vloc;                 // local col of component 0
  int vw = min(vbase + vloc, NVERT - 1);
  const float* wp = w + (size_t)vw * 5;
  float wr0 = wp[0], wr1 = wp[1], wr2 = wp[2], wr3 = wp[3], wr4 = wp[4];
  float vtr = vt[gc];
  __syncthreads();                     // Ss ready

  int nch = VBB / VCH;
  for (int ch = 0; ch < nch; ++ch) {
    int bb = b0 + ch * VCH;
    // issue A-chunk loads early (640 floats, coalesced) -> regs
    float ar0 = A[(size_t)bb * 80 + tid];
    float ar1 = A[(size_t)bb * 80 + tid + 128];
    float ar2 = A[(size_t)bb * 80 + tid + 256];
    float ar3 = A[(size_t)bb * 80 + tid + 384];
    float ar4 = A[(size_t)bb * 80 + tid + 512];
    // GEMM over K=86: 8 batch accumulators
    float a0 = vtr, a1 = vtr, a2 = vtr, a3 = vtr;
    float a4 = vtr, a5 = vtr, a6 = vtr, a7 = vtr;
    const float* gtb = Gt + bb;
#pragma unroll 2
    for (int k = 0; k < KK; ++k) {
      float sv = Ss[k * VBN + col];
      float4 g0 = *(const float4*)(gtb + (size_t)k * B);
      float4 g1 = *(const float4*)(gtb + (size_t)k * B + 4);
      a0 = fmaf(g0.x, sv, a0); a1 = fmaf(g0.y, sv, a1);
      a2 = fmaf(g0.z, sv, a2); a3 = fmaf(g0.w, sv, a3);
      a4 = fmaf(g1.x, sv, a4); a5 = fmaf(g1.y, sv, a5);
      a6 = fmaf(g1.z, sv, a6); a7 = fmaf(g1.w, sv, a7);
    }
    __syncthreads();                   // previous chunk's skin done with Cs/As
    As[tid]       = ar0;  As[tid + 128] = ar1;  As[tid + 256] = ar2;
    As[tid + 384] = ar3;  As[tid + 512] = ar4;
    if (act) {
      Cs[0][col] = a0; Cs[1][col] = a1; Cs[2][col] = a2; Cs[3][col] = a3;
      Cs[4][col] = a4; Cs[5][col] = a5; Cs[6][col] = a6; Cs[7][col] = a7;
    }
    __syncthreads();                   // Cs/As ready
    // skinning: T row q = sum_j w_j * A[b][j][q][:], then dot v_posed
    if (valid) {
#pragma unroll
      for (int j = 0; j < VCH; ++j) {
        const float* Ab = As + j * 80 + q * 4;
        float4 A0 = *(const float4*)(Ab);
        float4 A1 = *(const float4*)(Ab + 16);
        float4 A2 = *(const float4*)(Ab + 32);
        float4 A3 = *(const float4*)(Ab + 48);
        float4 A4 = *(const float4*)(Ab + 64);
        float T0 = fmaf(wr4, A4.x, fmaf(wr3, A3.x,
                   fmaf(wr2, A2.x, fmaf(wr1, A1.x, wr0 * A0.x))));
        float T1 = fmaf(wr4, A4.y, fmaf(wr3, A3.y,
                   fmaf(wr2, A2.y, fmaf(wr1, A1.y, wr0 * A0.y))));
        float T2 = fmaf(wr4, A4.z, fmaf(wr3, A3.z,
                   fmaf(wr2, A2.z, fmaf(wr1, A1.z, wr0 * A0.z))));
        float T3 = fmaf(wr4, A4.w, fmaf(wr3, A3.w,
                   fmaf(wr2, A2.w, fmaf(wr1, A1.w, wr0 * A0.w))));
        float x0 = Cs[j][colq], x1 = Cs[j][colq + 1], x2 = Cs[j][colq + 2];
        out[(size_t)(bb + j) * NV3 + gcol] =
            fmaf(T0, x0, fmaf(T1, x1, fmaf(T2, x2, T3)));
      }
    }
  }
}

extern "C" void kernel_launch(void* const* d_in, const int* in_sizes, int n_in,
                              void* d_out, int out_size, void* d_ws,
                              size_t ws_size, hipStream_t stream) {
  const float* expr = (const float*)d_in[0];
  const float* pose = (const float*)d_in[1];
  const float* vt   = (const float*)d_in[2];
  const float* sd   = (const float*)d_in[3];
  const float* pd   = (const float*)d_in[4];
  const float* Jr   = (const float*)d_in[5];
  const float* w    = (const float*)d_in[6];
  int B = in_sizes[0] / NEXP;

  float* out    = (float*)d_out;
  float* out_pf = out + (size_t)B * NV3;
  float* out_A  = out_pf + (size_t)B * NPF;
  float* ws     = (float*)d_ws;

  k_jreg<<<dim3(JBLK), 160, 0, stream>>>(Jr, sd, vt, ws);
  k_jred<<<dim3(3), 256, 0, stream>>>(ws);
  k_pose<<<dim3((B + 63) / 64), 64, 0, stream>>>(expr, pose, ws, out_pf,
                                                 out_A, B);
  k_vert<<<dim3((B + VBB - 1) / VBB, (NV3 + VBN - 1) / VBN), 128, 0, stream>>>(
      vt, sd, pd, w, out_A, ws + GT_OFF, out, B);
}